// Round 2
// baseline (490.103 us; speedup 1.0000x reference)
//
#include <hip/hip_runtime.h>
#include <hip/hip_fp16.h>

// Problem constants (B, CLEN, QLEN, H)
constexpr int NB = 16;
constexpr int CL = 4096;
constexpr int QL = 512;
constexpr int HD = 256;

typedef _Float16 f16x8 __attribute__((ext_vector_type(8)));
typedef _Float16 f16x4 __attribute__((ext_vector_type(4)));
typedef float    f32x4 __attribute__((ext_vector_type(4)));

// ---------------------------------------------------------------------------
// Workspace layout (bytes):
//   qph    : q*w_cq fp16 [b][j][d]   @ 0          (4,194,304)
//   qth    : q fp16 [b][d][j]        @ 4,194,304  (4,194,304)
//   qd2    : q.w_q+b_q+b_cq fp32     @ 8,388,608  (32,768)
//   cdot   : c.w_c+b_c fp32          @ 8,421,376  (262,144)
//   rowmax : fp32 NB*CL              @ 8,683,520  (262,144)
//   Mb     : fp32 NB                 @ 8,945,664
//   Zb     : fp32 NB                 @ 8,945,728
//   q2c    : fp32 NB*HD              @ 8,945,792  (16,384)
//   (sp eliminated — S/P never leave LDS)
// ---------------------------------------------------------------------------

// One wave per q-row: qph = fp16(q*w_cq) ; qd2 = q.w_q + b_q + b_cq
__global__ void k_prep_q(const float* __restrict__ q, const float* __restrict__ w_q,
                         const float* __restrict__ b_q, const float* __restrict__ w_cq,
                         const float* __restrict__ b_cq,
                         _Float16* __restrict__ qph, float* __restrict__ qd2) {
    int row  = blockIdx.x * 4 + (threadIdx.x >> 6);   // b*QL + j
    int lane = threadIdx.x & 63;
    float4 qv  = ((const float4*)(q + (size_t)row * HD))[lane];
    float4 wq  = ((const float4*)w_q)[lane];
    float4 wcq = ((const float4*)w_cq)[lane];
    f16x4 hv = {(_Float16)(qv.x * wcq.x), (_Float16)(qv.y * wcq.y),
                (_Float16)(qv.z * wcq.z), (_Float16)(qv.w * wcq.w)};
    *(f16x4*)(qph + (size_t)row * HD + lane * 4) = hv;
    float s = qv.x * wq.x + qv.y * wq.y + qv.z * wq.z + qv.w * wq.w;
    #pragma unroll
    for (int off = 32; off; off >>= 1) s += __shfl_down(s, off, 64);
    if (lane == 0) qd2[row] = s + b_q[0] + b_cq[0];
}

// One wave per c-row: cdot = c.w_c + b_c
__global__ void k_cdot(const float* __restrict__ c, const float* __restrict__ w_c,
                       const float* __restrict__ b_c, float* __restrict__ cdot) {
    int row  = blockIdx.x * 4 + (threadIdx.x >> 6);   // b*CL + i
    int lane = threadIdx.x & 63;
    float4 cv = ((const float4*)(c + (size_t)row * HD))[lane];
    float4 wv = ((const float4*)w_c)[lane];
    float s = cv.x * wv.x + cv.y * wv.y + cv.z * wv.z + cv.w * wv.w;
    #pragma unroll
    for (int off = 32; off; off >>= 1) s += __shfl_down(s, off, 64);
    if (lane == 0) cdot[row] = s + b_c[0];
}

// LDS transpose: qth[b][d][j] = fp16(q[b][j][d]); 64x64 tiles
__global__ void k_tq(const float* __restrict__ q, _Float16* __restrict__ qth) {
    __shared__ float tile[64][65];
    int b  = blockIdx.z;
    int d0 = blockIdx.x * 64;
    int j0 = blockIdx.y * 64;
    int t  = threadIdx.x;
    int rr = t >> 4, cseg = t & 15;
    #pragma unroll
    for (int p = 0; p < 4; ++p) {
        int r = rr + p * 16;   // j-row within tile
        float4 v = *(const float4*)(q + ((size_t)b * QL + j0 + r) * HD + d0 + cseg * 4);
        tile[r][cseg * 4 + 0] = v.x; tile[r][cseg * 4 + 1] = v.y;
        tile[r][cseg * 4 + 2] = v.z; tile[r][cseg * 4 + 3] = v.w;
    }
    __syncthreads();
    #pragma unroll
    for (int p = 0; p < 4; ++p) {
        int dr = rr + p * 16;  // d-row within tile
        f16x4 hv = {(_Float16)tile[cseg * 4 + 0][dr], (_Float16)tile[cseg * 4 + 1][dr],
                    (_Float16)tile[cseg * 4 + 2][dr], (_Float16)tile[cseg * 4 + 3][dr]};
        *(f16x4*)(qth + ((size_t)b * HD + d0 + dr) * QL + j0 + cseg * 4) = hv;
    }
}

// ---------------------------------------------------------------------------
// Fused kernel: per 64 c-rows of one batch, 8 waves (512 thr):
//   GEMM1 (swapped): S^T = qph @ c^T, wave jw owns j-slab of 64, all 64 i.
//   softmax over j: lane-local (16 vals) + shfl over quads + cross-wave LDS.
//   P (fp16) -> LDS [64][512] (XOR-swizzled); GEMM2: c2q = P @ qth.
//   Epilogue writes x[1]=c2q, x[2]=c*c2q. (x[0],x[3] in k_x03.)
// LDS (64KB, time-shared):
//   phase 1: qphL [512 j][64 k] fp16 (one 64-wide K chunk), swizzled
//   phase 2: redM [8][64] f32 @0, redZ [8][64] f32 @2048
//   phase 3: PL   [64 i][512 j] fp16, swizzled
// Swizzle: byte ^= (row & 7) << 4  (rows stride 128B/1024B -> 2-way only)
// ---------------------------------------------------------------------------
__launch_bounds__(512, 4)
__global__ void k_fused(const float* __restrict__ c, const _Float16* __restrict__ qph,
                        const float* __restrict__ qd2, const _Float16* __restrict__ qth,
                        float* __restrict__ rowmax, float* __restrict__ x) {
    __shared__ __align__(1024) char smem[65536];

    const int b  = blockIdx.y;
    const int i0 = blockIdx.x * 64;
    const int t  = threadIdx.x;
    const int wave = t >> 6;
    const int ln   = t & 15;
    const int quad = (t >> 4) & 3;
    const int jw   = wave;              // GEMM1: j-slab of 64

    // ---------------- GEMM1: acc[mt][nt] = S^T fragment (j=row, i=col) --------
    f32x4 acc[4][4];
    #pragma unroll
    for (int mt = 0; mt < 4; ++mt)
        #pragma unroll
        for (int nt = 0; nt < 4; ++nt) acc[mt][nt] = (f32x4){0.f, 0.f, 0.f, 0.f};

    for (int dc = 0; dc < 4; ++dc) {               // K chunks of 64 over HD=256
        __syncthreads();
        {   // stage qph[b][0..512)[dc*64..+64) -> qphL (swizzled, 64KB)
            const int row = t >> 3, seg = t & 7;
            #pragma unroll
            for (int p = 0; p < 8; ++p) {
                int j = row + p * 64;
                f16x8 hv = *(const f16x8*)(qph + ((size_t)b * QL + j) * HD + dc * 64 + seg * 8);
                int byte = (j << 7) + (seg << 4);
                byte ^= (j & 7) << 4;
                *(f16x8*)(smem + byte) = hv;
            }
        }
        __syncthreads();
        #pragma unroll
        for (int ks = 0; ks < 2; ++ks) {           // two k=32 MFMA steps
            f16x8 bf[4];                           // B = c rows (fp32 -> fp16)
            #pragma unroll
            for (int nt = 0; nt < 4; ++nt) {
                const float* src = c + ((size_t)b * CL + i0 + nt * 16 + ln) * HD
                                     + dc * 64 + ks * 32 + quad * 8;
                float4 v0 = *(const float4*)src;
                float4 v1 = *(const float4*)(src + 4);
                bf[nt] = (f16x8){(_Float16)v0.x, (_Float16)v0.y, (_Float16)v0.z, (_Float16)v0.w,
                                 (_Float16)v1.x, (_Float16)v1.y, (_Float16)v1.z, (_Float16)v1.w};
            }
            #pragma unroll
            for (int mt = 0; mt < 4; ++mt) {       // A = qph rows (j) from LDS
                int j = jw * 64 + mt * 16 + ln;
                int byte = (j << 7) + (ks * 64 + quad * 16);
                byte ^= (j & 7) << 4;
                f16x8 af = *(const f16x8*)(smem + byte);
                #pragma unroll
                for (int nt = 0; nt < 4; ++nt)
                    acc[mt][nt] = __builtin_amdgcn_mfma_f32_16x16x32_f16(af, bf[nt], acc[mt][nt], 0, 0, 0);
            }
        }
    }
    // lane holds: j = jw*64 + mt*16 + quad*4 + r ; i = nt*16 + ln

    // ---------------- softmax over j (512) ------------------------------------
    float m[4];
    #pragma unroll
    for (int nt = 0; nt < 4; ++nt) m[nt] = -1e30f;
    #pragma unroll
    for (int mt = 0; mt < 4; ++mt) {
        float4 qv = *(const float4*)(qd2 + b * QL + jw * 64 + mt * 16 + quad * 4);
        #pragma unroll
        for (int nt = 0; nt < 4; ++nt) {
            acc[mt][nt][0] += qv.x; acc[mt][nt][1] += qv.y;
            acc[mt][nt][2] += qv.z; acc[mt][nt][3] += qv.w;
            m[nt] = fmaxf(m[nt], fmaxf(fmaxf(acc[mt][nt][0], acc[mt][nt][1]),
                                       fmaxf(acc[mt][nt][2], acc[mt][nt][3])));
        }
    }
    #pragma unroll
    for (int nt = 0; nt < 4; ++nt) {               // reduce over quads
        m[nt] = fmaxf(m[nt], __shfl_xor(m[nt], 16, 64));
        m[nt] = fmaxf(m[nt], __shfl_xor(m[nt], 32, 64));
    }
    __syncthreads();                               // last qphL reads done; overlay
    float* redM = (float*)smem;                    // [8][64]
    float* redZ = (float*)(smem + 2048);           // [8][64]
    if (quad == 0) {
        #pragma unroll
        for (int nt = 0; nt < 4; ++nt) redM[jw * 64 + nt * 16 + ln] = m[nt];
    }
    __syncthreads();
    #pragma unroll
    for (int nt = 0; nt < 4; ++nt) {
        int ri = nt * 16 + ln;
        float mm = redM[ri];
        #pragma unroll
        for (int w = 1; w < 8; ++w) mm = fmaxf(mm, redM[w * 64 + ri]);
        m[nt] = mm;
    }
    if (jw == 0 && quad == 0) {
        #pragma unroll
        for (int nt = 0; nt < 4; ++nt)
            rowmax[(size_t)b * CL + i0 + nt * 16 + ln] = m[nt];
    }
    float z[4] = {0.f, 0.f, 0.f, 0.f};
    #pragma unroll
    for (int mt = 0; mt < 4; ++mt)
        #pragma unroll
        for (int nt = 0; nt < 4; ++nt) {
            #pragma unroll
            for (int r = 0; r < 4; ++r) {
                float e = __expf(acc[mt][nt][r] - m[nt]);
                acc[mt][nt][r] = e;
                z[nt] += e;
            }
        }
    #pragma unroll
    for (int nt = 0; nt < 4; ++nt) {
        z[nt] += __shfl_xor(z[nt], 16, 64);
        z[nt] += __shfl_xor(z[nt], 32, 64);
    }
    if (quad == 0) {
        #pragma unroll
        for (int nt = 0; nt < 4; ++nt) redZ[jw * 64 + nt * 16 + ln] = z[nt];
    }
    __syncthreads();
    float inv[4];
    #pragma unroll
    for (int nt = 0; nt < 4; ++nt) {
        int ri = nt * 16 + ln;
        float zz = redZ[ri];
        #pragma unroll
        for (int w = 1; w < 8; ++w) zz += redZ[w * 64 + ri];
        inv[nt] = 1.0f / zz;
    }
    __syncthreads();                               // redZ reads done before P write

    // ---------------- P (fp16) -> LDS [64][512] swizzled -----------------------
    #pragma unroll
    for (int mt = 0; mt < 4; ++mt) {
        int jcol = jw * 64 + mt * 16 + quad * 4;
        #pragma unroll
        for (int nt = 0; nt < 4; ++nt) {
            int i = nt * 16 + ln;
            f16x4 hv = {(_Float16)(acc[mt][nt][0] * inv[nt]),
                        (_Float16)(acc[mt][nt][1] * inv[nt]),
                        (_Float16)(acc[mt][nt][2] * inv[nt]),
                        (_Float16)(acc[mt][nt][3] * inv[nt])};
            int byte = (i << 10) + (jcol << 1);
            byte ^= (i & 7) << 4;
            *(f16x4*)(smem + byte) = hv;
        }
    }
    __syncthreads();

    // ---------------- GEMM2: c2q = P @ qth ; wave = 32 i x 64 d ----------------
    const int iw = wave >> 2;          // 0..1
    const int dw = wave & 3;           // 0..3
    f32x4 acc2[2][4];
    #pragma unroll
    for (int it = 0; it < 2; ++it)
        #pragma unroll
        for (int dt = 0; dt < 4; ++dt) acc2[it][dt] = (f32x4){0.f, 0.f, 0.f, 0.f};

    const _Float16* qthb = qth + (size_t)b * HD * QL;
    #pragma unroll 4
    for (int kc = 0; kc < 16; ++kc) {              // K chunks of 32 over QL=512
        f16x8 af[2], bf[4];
        #pragma unroll
        for (int it = 0; it < 2; ++it) {           // A = P rows (i), LDS swizzled
            int i = iw * 32 + it * 16 + ln;
            int byte = (i << 10) + (kc * 64 + quad * 16);
            byte ^= (i & 7) << 4;
            af[it] = *(const f16x8*)(smem + byte);
        }
        #pragma unroll
        for (int dt = 0; dt < 4; ++dt)             // B = qth rows (d), global (L2-hot)
            bf[dt] = *(const f16x8*)(qthb + (size_t)(dw * 64 + dt * 16 + ln) * QL
                                     + kc * 32 + quad * 8);
        #pragma unroll
        for (int it = 0; it < 2; ++it)
            #pragma unroll
            for (int dt = 0; dt < 4; ++dt)
                acc2[it][dt] = __builtin_amdgcn_mfma_f32_16x16x32_f16(af[it], bf[dt], acc2[it][dt], 0, 0, 0);
    }

    // ---------------- epilogue: x[1]=c2q, x[2]=c*c2q ---------------------------
    #pragma unroll
    for (int it = 0; it < 2; ++it) {
        #pragma unroll
        for (int r = 0; r < 4; ++r) {
            int i = i0 + iw * 32 + it * 16 + quad * 4 + r;
            const float* crow = c + ((size_t)b * CL + i) * HD;
            float* xrow = x + ((size_t)b * CL + i) * (4 * HD);
            #pragma unroll
            for (int dt = 0; dt < 4; ++dt) {
                int d = dw * 64 + dt * 16 + ln;
                float cv = crow[d];
                float a  = acc2[it][dt][r];
                xrow[HD + d]     = a;
                xrow[2 * HD + d] = cv * a;
            }
        }
    }
}

// Per-batch M,Z over i of (rowmax + cdot); also zero-init q2c accumulators
__global__ void k_batch_mz(const float* __restrict__ rowmax, const float* __restrict__ cdot,
                           float* __restrict__ Mb, float* __restrict__ Zb,
                           float* __restrict__ q2c) {
    int b = blockIdx.x, t = threadIdx.x;
    q2c[b * HD + t] = 0.f;
    float vals[16];
    float m = -1e30f;
    #pragma unroll
    for (int k = 0; k < 16; ++k) {
        int i = t + k * 256;
        vals[k] = rowmax[b * CL + i] + cdot[b * CL + i];
        m = fmaxf(m, vals[k]);
    }
    __shared__ float redm[4], redz[4];
    #pragma unroll
    for (int off = 32; off; off >>= 1) m = fmaxf(m, __shfl_xor(m, off, 64));
    if ((t & 63) == 0) redm[t >> 6] = m;
    __syncthreads();
    m = fmaxf(fmaxf(redm[0], redm[1]), fmaxf(redm[2], redm[3]));
    float z = 0.f;
    #pragma unroll
    for (int k = 0; k < 16; ++k) z += __expf(vals[k] - m);
    #pragma unroll
    for (int off = 32; off; off >>= 1) z += __shfl_xor(z, off, 64);
    if ((t & 63) == 0) redz[t >> 6] = z;
    __syncthreads();
    if (t == 0) { Mb[b] = m; Zb[b] = redz[0] + redz[1] + redz[2] + redz[3]; }
}

// q2c[b][d] = sum_i softmax_i(rowmax+cdot) * c[b][i][d]
__global__ void k_q2c(const float* __restrict__ c, const float* __restrict__ rowmax,
                      const float* __restrict__ cdot, const float* __restrict__ Mb,
                      const float* __restrict__ Zb, float* __restrict__ q2c) {
    int b = blockIdx.x >> 6, slab = blockIdx.x & 63;
    int dd = threadIdx.x;
    float M = Mb[b], invZ = 1.0f / Zb[b];
    float acc = 0.f;
    for (int r = 0; r < 64; ++r) {
        int i = slab * 64 + r;
        float w = __expf(rowmax[b * CL + i] + cdot[b * CL + i] - M);
        acc += w * c[((size_t)b * CL + i) * HD + dd];
    }
    atomicAdd(&q2c[b * HD + dd], acc * invZ);
}

// x[0] and x[3] quarters: x[...][d] = c ; x[...][3H+d] = c * q2c
__global__ void k_x03(const float* __restrict__ c, const float* __restrict__ q2c,
                      float* __restrict__ x) {
    int row  = blockIdx.x * 4 + (threadIdx.x >> 6);   // b*CL + i
    int lane = threadIdx.x & 63;
    int b = row >> 12;                                 // CL = 4096
    float4 cv = ((const float4*)(c + (size_t)row * HD))[lane];
    float4 qv = ((const float4*)(q2c + b * HD))[lane];
    float4 o  = {cv.x * qv.x, cv.y * qv.y, cv.z * qv.z, cv.w * qv.w};
    float* xrow = x + (size_t)row * (4 * HD);
    ((float4*)xrow)[lane]            = cv;
    ((float4*)(xrow + 3 * HD))[lane] = o;
}

extern "C" void kernel_launch(void* const* d_in, const int* in_sizes, int n_in,
                              void* d_out, int out_size, void* d_ws, size_t ws_size,
                              hipStream_t stream) {
    const float* c    = (const float*)d_in[0];
    const float* q    = (const float*)d_in[1];
    const float* w_c  = (const float*)d_in[2];
    const float* b_c  = (const float*)d_in[3];
    const float* w_q  = (const float*)d_in[4];
    const float* b_q  = (const float*)d_in[5];
    const float* w_cq = (const float*)d_in[6];
    const float* b_cq = (const float*)d_in[7];
    float* x = (float*)d_out;

    char* ws = (char*)d_ws;
    _Float16* qph  = (_Float16*)(ws);
    _Float16* qth  = (_Float16*)(ws + 4194304);
    float*  qd2    = (float*)(ws + 8388608);
    float*  cdot   = (float*)(ws + 8421376);
    float*  rowmax = (float*)(ws + 8683520);
    float*  Mb     = (float*)(ws + 8945664);
    float*  Zb     = (float*)(ws + 8945728);
    float*  q2c    = (float*)(ws + 8945792);

    k_prep_q<<<NB * QL / 4, 256, 0, stream>>>(q, w_q, b_q, w_cq, b_cq, qph, qd2);
    k_cdot<<<NB * CL / 4, 256, 0, stream>>>(c, w_c, b_c, cdot);
    k_tq<<<dim3(HD / 64, QL / 64, NB), 256, 0, stream>>>(q, qth);
    k_fused<<<dim3(CL / 64, NB), 512, 0, stream>>>(c, qph, qd2, qth, rowmax, x);
    k_batch_mz<<<NB, 256, 0, stream>>>(rowmax, cdot, Mb, Zb, q2c);
    k_q2c<<<NB * 64, 256, 0, stream>>>(c, rowmax, cdot, Mb, Zb, q2c);
    k_x03<<<NB * CL / 4, 256, 0, stream>>>(c, q2c, x);
}

// Round 3
// 472.321 us; speedup vs baseline: 1.0376x; 1.0376x over previous
//
#include <hip/hip_runtime.h>
#include <hip/hip_fp16.h>

// Problem constants (B, CLEN, QLEN, H)
constexpr int NB = 16;
constexpr int CL = 4096;
constexpr int QL = 512;
constexpr int HD = 256;

typedef _Float16 f16x8 __attribute__((ext_vector_type(8)));
typedef _Float16 f16x4 __attribute__((ext_vector_type(4)));
typedef float    f32x4 __attribute__((ext_vector_type(4)));

typedef __attribute__((address_space(3))) void lds_void;
typedef __attribute__((address_space(1))) const void glb_void;

// ---------------------------------------------------------------------------
// Workspace layout (bytes):
//   qph    : q*w_cq fp16 [b][j][d]   @ 0          (4,194,304)
//   qth    : q fp16 [b][d][j]        @ 4,194,304  (4,194,304)
//   qd2    : q.w_q+b_q+b_cq fp32     @ 8,388,608  (32,768)
//   cdot   : c.w_c+b_c fp32          @ 8,421,376  (262,144)
//   rowmax : fp32 NB*CL              @ 8,683,520  (262,144)
//   Mb     : fp32 NB                 @ 8,945,664
//   Zb     : fp32 NB                 @ 8,945,728
//   q2c    : fp32 NB*HD              @ 8,945,792  (16,384)
// ---------------------------------------------------------------------------

// One wave per q-row: qph = fp16(q*w_cq) ; qd2 = q.w_q + b_q + b_cq
__global__ void k_prep_q(const float* __restrict__ q, const float* __restrict__ w_q,
                         const float* __restrict__ b_q, const float* __restrict__ w_cq,
                         const float* __restrict__ b_cq,
                         _Float16* __restrict__ qph, float* __restrict__ qd2) {
    int row  = blockIdx.x * 4 + (threadIdx.x >> 6);   // b*QL + j
    int lane = threadIdx.x & 63;
    float4 qv  = ((const float4*)(q + (size_t)row * HD))[lane];
    float4 wq  = ((const float4*)w_q)[lane];
    float4 wcq = ((const float4*)w_cq)[lane];
    f16x4 hv = {(_Float16)(qv.x * wcq.x), (_Float16)(qv.y * wcq.y),
                (_Float16)(qv.z * wcq.z), (_Float16)(qv.w * wcq.w)};
    *(f16x4*)(qph + (size_t)row * HD + lane * 4) = hv;
    float s = qv.x * wq.x + qv.y * wq.y + qv.z * wq.z + qv.w * wq.w;
    #pragma unroll
    for (int off = 32; off; off >>= 1) s += __shfl_down(s, off, 64);
    if (lane == 0) qd2[row] = s + b_q[0] + b_cq[0];
}

// One wave per c-row: cdot = c.w_c + b_c
__global__ void k_cdot(const float* __restrict__ c, const float* __restrict__ w_c,
                       const float* __restrict__ b_c, float* __restrict__ cdot) {
    int row  = blockIdx.x * 4 + (threadIdx.x >> 6);   // b*CL + i
    int lane = threadIdx.x & 63;
    float4 cv = ((const float4*)(c + (size_t)row * HD))[lane];
    float4 wv = ((const float4*)w_c)[lane];
    float s = cv.x * wv.x + cv.y * wv.y + cv.z * wv.z + cv.w * wv.w;
    #pragma unroll
    for (int off = 32; off; off >>= 1) s += __shfl_down(s, off, 64);
    if (lane == 0) cdot[row] = s + b_c[0];
}

// LDS transpose: qth[b][d][j] = fp16(q[b][j][d]); 64x64 tiles
__global__ void k_tq(const float* __restrict__ q, _Float16* __restrict__ qth) {
    __shared__ float tile[64][65];
    int b  = blockIdx.z;
    int d0 = blockIdx.x * 64;
    int j0 = blockIdx.y * 64;
    int t  = threadIdx.x;
    int rr = t >> 4, cseg = t & 15;
    #pragma unroll
    for (int p = 0; p < 4; ++p) {
        int r = rr + p * 16;   // j-row within tile
        float4 v = *(const float4*)(q + ((size_t)b * QL + j0 + r) * HD + d0 + cseg * 4);
        tile[r][cseg * 4 + 0] = v.x; tile[r][cseg * 4 + 1] = v.y;
        tile[r][cseg * 4 + 2] = v.z; tile[r][cseg * 4 + 3] = v.w;
    }
    __syncthreads();
    #pragma unroll
    for (int p = 0; p < 4; ++p) {
        int dr = rr + p * 16;  // d-row within tile
        f16x4 hv = {(_Float16)tile[cseg * 4 + 0][dr], (_Float16)tile[cseg * 4 + 1][dr],
                    (_Float16)tile[cseg * 4 + 2][dr], (_Float16)tile[cseg * 4 + 3][dr]};
        *(f16x4*)(qth + ((size_t)b * HD + d0 + dr) * QL + j0 + cseg * 4) = hv;
    }
}

// ---------------------------------------------------------------------------
// Fused kernel: per 64 c-rows of one batch, 8 waves (512 thr):
//   GEMM1 (swapped): S^T = qph @ c^T; wave jw owns j-slab of 64, all 64 i.
//     qph slab staged per-wave via global_load_lds (NO barriers), 8 K-chunks
//     of 32, double-buffered, counted vmcnt(4). Pre-swizzled global source +
//     linear LDS dest + swizzled read (bank-conflict-free).
//   softmax over j: lane-local + shfl over quads + cross-wave LDS reduce.
//   P (fp16) -> LDS [64][512] (XOR-swizzled); GEMM2: c2q = P @ qth.
//   Epilogue writes x[1]=c2q, x[2]=c*c2q. (x[0],x[3] in k_x03.)
// LDS (64KB static, time-shared):
//   phase 1: qphL = 2 bufs x 8 slabs(wave) x 64 rows x 64B   (2 x 32KB)
//   phase 2: redM [8][64] f32 @0, redZ [8][64] f32 @2048
//   phase 3: PL [64 i][512 j] fp16, swizzled byte ^= (i&7)<<4
// ---------------------------------------------------------------------------
__launch_bounds__(512, 2)
__global__ void k_fused(const float* __restrict__ c, const _Float16* __restrict__ qph,
                        const float* __restrict__ qd2, const _Float16* __restrict__ qth,
                        float* __restrict__ rowmax, float* __restrict__ x) {
    __shared__ __align__(1024) char smem[65536];

    const int b  = blockIdx.y;
    const int i0 = blockIdx.x * 64;
    const int t  = threadIdx.x;
    const int wave = t >> 6;
    const int l    = t & 63;
    const int ln   = t & 15;
    const int quad = (t >> 4) & 3;
    const int jw   = wave;              // GEMM1: j-slab of 64

    // per-lane swizzled global segment: LDS[row][seg] = qph_row[seg ^ ((row>>1)&3)]
    const int srcseg = (l & 3) ^ ((l >> 3) & 3);
    const _Float16* qpb = qph + ((size_t)b * QL + jw * 64) * HD;

    // ---------------- GEMM1: acc[mt][nt] = S^T fragment (j=row, i=col) --------
    f32x4 acc[4][4];
    #pragma unroll
    for (int mt = 0; mt < 4; ++mt)
        #pragma unroll
        for (int nt = 0; nt < 4; ++nt) acc[mt][nt] = (f32x4){0.f, 0.f, 0.f, 0.f};

    // prologue: issue chunk 0 into buf 0
    #pragma unroll
    for (int p = 0; p < 4; ++p) {
        const _Float16* src = qpb + (size_t)(p * 16 + (l >> 2)) * HD + srcseg * 8;
        char* dst = smem + jw * 4096 + p * 1024;     // wave-uniform base
        __builtin_amdgcn_global_load_lds((glb_void*)src, (lds_void*)dst, 16, 0, 0);
    }

    const int xq = (ln >> 1) & 3;                    // read-side swizzle component
    for (int ch = 0; ch < 8; ++ch) {
        if (ch < 7) {                                // issue next chunk, other buffer
            const int buf = (ch + 1) & 1;
            #pragma unroll
            for (int p = 0; p < 4; ++p) {
                const _Float16* src = qpb + (size_t)(p * 16 + (l >> 2)) * HD
                                    + (ch + 1) * 32 + srcseg * 8;
                char* dst = smem + buf * 32768 + jw * 4096 + p * 1024;
                __builtin_amdgcn_global_load_lds((glb_void*)src, (lds_void*)dst, 16, 0, 0);
            }
            asm volatile("s_waitcnt vmcnt(4)" ::: "memory");   // ch's 4 done, ch+1 in flight
        } else {
            asm volatile("s_waitcnt vmcnt(0)" ::: "memory");
        }
        f16x8 bf[4];                                 // B = c rows (fp32 -> fp16, L1-hot)
        #pragma unroll
        for (int nt = 0; nt < 4; ++nt) {
            const float* srcc = c + ((size_t)b * CL + i0 + nt * 16 + ln) * HD
                              + ch * 32 + quad * 8;
            float4 v0 = *(const float4*)srcc;
            float4 v1 = *(const float4*)(srcc + 4);
            bf[nt] = (f16x8){(_Float16)v0.x, (_Float16)v0.y, (_Float16)v0.z, (_Float16)v0.w,
                             (_Float16)v1.x, (_Float16)v1.y, (_Float16)v1.z, (_Float16)v1.w};
        }
        #pragma unroll
        for (int mt = 0; mt < 4; ++mt) {             // A = qph slab rows (j) from LDS
            int rr = mt * 16 + ln;
            const char* ap = smem + (ch & 1) * 32768 + jw * 4096 + rr * 64
                           + ((quad ^ xq) << 4);
            f16x8 af = *(const f16x8*)ap;
            #pragma unroll
            for (int nt = 0; nt < 4; ++nt)
                acc[mt][nt] = __builtin_amdgcn_mfma_f32_16x16x32_f16(af, bf[nt], acc[mt][nt], 0, 0, 0);
        }
    }
    // lane holds: j = jw*64 + mt*16 + quad*4 + r ; i = nt*16 + ln

    // ---------------- softmax over j (512) ------------------------------------
    float m[4];
    #pragma unroll
    for (int nt = 0; nt < 4; ++nt) m[nt] = -1e30f;
    #pragma unroll
    for (int mt = 0; mt < 4; ++mt) {
        float4 qv = *(const float4*)(qd2 + b * QL + jw * 64 + mt * 16 + quad * 4);
        #pragma unroll
        for (int nt = 0; nt < 4; ++nt) {
            acc[mt][nt][0] += qv.x; acc[mt][nt][1] += qv.y;
            acc[mt][nt][2] += qv.z; acc[mt][nt][3] += qv.w;
            m[nt] = fmaxf(m[nt], fmaxf(fmaxf(acc[mt][nt][0], acc[mt][nt][1]),
                                       fmaxf(acc[mt][nt][2], acc[mt][nt][3])));
        }
    }
    #pragma unroll
    for (int nt = 0; nt < 4; ++nt) {               // reduce over quads
        m[nt] = fmaxf(m[nt], __shfl_xor(m[nt], 16, 64));
        m[nt] = fmaxf(m[nt], __shfl_xor(m[nt], 32, 64));
    }
    __syncthreads();                               // all GEMM1 LDS reads done; overlay
    float* redM = (float*)smem;                    // [8][64]
    float* redZ = (float*)(smem + 2048);           // [8][64]
    if (quad == 0) {
        #pragma unroll
        for (int nt = 0; nt < 4; ++nt) redM[jw * 64 + nt * 16 + ln] = m[nt];
    }
    __syncthreads();
    #pragma unroll
    for (int nt = 0; nt < 4; ++nt) {
        int ri = nt * 16 + ln;
        float mm = redM[ri];
        #pragma unroll
        for (int w = 1; w < 8; ++w) mm = fmaxf(mm, redM[w * 64 + ri]);
        m[nt] = mm;
    }
    if (jw == 0 && quad == 0) {
        #pragma unroll
        for (int nt = 0; nt < 4; ++nt)
            rowmax[(size_t)b * CL + i0 + nt * 16 + ln] = m[nt];
    }
    float z[4] = {0.f, 0.f, 0.f, 0.f};
    #pragma unroll
    for (int mt = 0; mt < 4; ++mt)
        #pragma unroll
        for (int nt = 0; nt < 4; ++nt) {
            #pragma unroll
            for (int r = 0; r < 4; ++r) {
                float e = __expf(acc[mt][nt][r] - m[nt]);
                acc[mt][nt][r] = e;
                z[nt] += e;
            }
        }
    #pragma unroll
    for (int nt = 0; nt < 4; ++nt) {
        z[nt] += __shfl_xor(z[nt], 16, 64);
        z[nt] += __shfl_xor(z[nt], 32, 64);
    }
    if (quad == 0) {
        #pragma unroll
        for (int nt = 0; nt < 4; ++nt) redZ[jw * 64 + nt * 16 + ln] = z[nt];
    }
    __syncthreads();
    float inv[4];
    #pragma unroll
    for (int nt = 0; nt < 4; ++nt) {
        int ri = nt * 16 + ln;
        float zz = redZ[ri];
        #pragma unroll
        for (int w = 1; w < 8; ++w) zz += redZ[w * 64 + ri];
        inv[nt] = 1.0f / zz;
    }
    __syncthreads();                               // redZ reads done before P write

    // ---------------- P (fp16) -> LDS [64][512] swizzled -----------------------
    #pragma unroll
    for (int mt = 0; mt < 4; ++mt) {
        int jcol = jw * 64 + mt * 16 + quad * 4;
        #pragma unroll
        for (int nt = 0; nt < 4; ++nt) {
            int i = nt * 16 + ln;
            f16x4 hv = {(_Float16)(acc[mt][nt][0] * inv[nt]),
                        (_Float16)(acc[mt][nt][1] * inv[nt]),
                        (_Float16)(acc[mt][nt][2] * inv[nt]),
                        (_Float16)(acc[mt][nt][3] * inv[nt])};
            int byte = (i << 10) + (jcol << 1);
            byte ^= (i & 7) << 4;
            *(f16x4*)(smem + byte) = hv;
        }
    }
    __syncthreads();

    // ---------------- GEMM2: c2q = P @ qth ; wave = 32 i x 64 d ----------------
    const int iw = wave >> 2;          // 0..1
    const int dw = wave & 3;           // 0..3
    f32x4 acc2[2][4];
    #pragma unroll
    for (int it = 0; it < 2; ++it)
        #pragma unroll
        for (int dt = 0; dt < 4; ++dt) acc2[it][dt] = (f32x4){0.f, 0.f, 0.f, 0.f};

    const _Float16* qthb = qth + (size_t)b * HD * QL;
    #pragma unroll 4
    for (int kc = 0; kc < 16; ++kc) {              // K chunks of 32 over QL=512
        f16x8 af[2], bf[4];
        #pragma unroll
        for (int it = 0; it < 2; ++it) {           // A = P rows (i), LDS swizzled
            int i = iw * 32 + it * 16 + ln;
            int byte = (i << 10) + (kc * 64 + quad * 16);
            byte ^= (i & 7) << 4;
            af[it] = *(const f16x8*)(smem + byte);
        }
        #pragma unroll
        for (int dt = 0; dt < 4; ++dt)             // B = qth rows (d), global (L2-hot)
            bf[dt] = *(const f16x8*)(qthb + (size_t)(dw * 64 + dt * 16 + ln) * QL
                                     + kc * 32 + quad * 8);
        #pragma unroll
        for (int it = 0; it < 2; ++it)
            #pragma unroll
            for (int dt = 0; dt < 4; ++dt)
                acc2[it][dt] = __builtin_amdgcn_mfma_f32_16x16x32_f16(af[it], bf[dt], acc2[it][dt], 0, 0, 0);
    }

    // ---------------- epilogue: x[1]=c2q, x[2]=c*c2q ---------------------------
    #pragma unroll
    for (int it = 0; it < 2; ++it) {
        #pragma unroll
        for (int r = 0; r < 4; ++r) {
            int i = i0 + iw * 32 + it * 16 + quad * 4 + r;
            const float* crow = c + ((size_t)b * CL + i) * HD;
            float* xrow = x + ((size_t)b * CL + i) * (4 * HD);
            #pragma unroll
            for (int dt = 0; dt < 4; ++dt) {
                int d = dw * 64 + dt * 16 + ln;
                float cv = crow[d];
                float a  = acc2[it][dt][r];
                xrow[HD + d]     = a;
                xrow[2 * HD + d] = cv * a;
            }
        }
    }
}

// Per-batch M,Z over i of (rowmax + cdot); also zero-init q2c accumulators
__global__ void k_batch_mz(const float* __restrict__ rowmax, const float* __restrict__ cdot,
                           float* __restrict__ Mb, float* __restrict__ Zb,
                           float* __restrict__ q2c) {
    int b = blockIdx.x, t = threadIdx.x;
    q2c[b * HD + t] = 0.f;
    float vals[16];
    float m = -1e30f;
    #pragma unroll
    for (int k = 0; k < 16; ++k) {
        int i = t + k * 256;
        vals[k] = rowmax[b * CL + i] + cdot[b * CL + i];
        m = fmaxf(m, vals[k]);
    }
    __shared__ float redm[4], redz[4];
    #pragma unroll
    for (int off = 32; off; off >>= 1) m = fmaxf(m, __shfl_xor(m, off, 64));
    if ((t & 63) == 0) redm[t >> 6] = m;
    __syncthreads();
    m = fmaxf(fmaxf(redm[0], redm[1]), fmaxf(redm[2], redm[3]));
    float z = 0.f;
    #pragma unroll
    for (int k = 0; k < 16; ++k) z += __expf(vals[k] - m);
    #pragma unroll
    for (int off = 32; off; off >>= 1) z += __shfl_xor(z, off, 64);
    if ((t & 63) == 0) redz[t >> 6] = z;
    __syncthreads();
    if (t == 0) { Mb[b] = m; Zb[b] = redz[0] + redz[1] + redz[2] + redz[3]; }
}

// q2c[b][d] = sum_i softmax_i(rowmax+cdot) * c[b][i][d]
__global__ void k_q2c(const float* __restrict__ c, const float* __restrict__ rowmax,
                      const float* __restrict__ cdot, const float* __restrict__ Mb,
                      const float* __restrict__ Zb, float* __restrict__ q2c) {
    int b = blockIdx.x >> 6, slab = blockIdx.x & 63;
    int dd = threadIdx.x;
    float M = Mb[b], invZ = 1.0f / Zb[b];
    float acc = 0.f;
    for (int r = 0; r < 64; ++r) {
        int i = slab * 64 + r;
        float w = __expf(rowmax[b * CL + i] + cdot[b * CL + i] - M);
        acc += w * c[((size_t)b * CL + i) * HD + dd];
    }
    atomicAdd(&q2c[b * HD + dd], acc * invZ);
}

// x[0] and x[3] quarters: x[...][d] = c ; x[...][3H+d] = c * q2c
__global__ void k_x03(const float* __restrict__ c, const float* __restrict__ q2c,
                      float* __restrict__ x) {
    int row  = blockIdx.x * 4 + (threadIdx.x >> 6);   // b*CL + i
    int lane = threadIdx.x & 63;
    int b = row >> 12;                                 // CL = 4096
    float4 cv = ((const float4*)(c + (size_t)row * HD))[lane];
    float4 qv = ((const float4*)(q2c + b * HD))[lane];
    float4 o  = {cv.x * qv.x, cv.y * qv.y, cv.z * qv.z, cv.w * qv.w};
    float* xrow = x + (size_t)row * (4 * HD);
    ((float4*)xrow)[lane]            = cv;
    ((float4*)(xrow + 3 * HD))[lane] = o;
}

extern "C" void kernel_launch(void* const* d_in, const int* in_sizes, int n_in,
                              void* d_out, int out_size, void* d_ws, size_t ws_size,
                              hipStream_t stream) {
    const float* c    = (const float*)d_in[0];
    const float* q    = (const float*)d_in[1];
    const float* w_c  = (const float*)d_in[2];
    const float* b_c  = (const float*)d_in[3];
    const float* w_q  = (const float*)d_in[4];
    const float* b_q  = (const float*)d_in[5];
    const float* w_cq = (const float*)d_in[6];
    const float* b_cq = (const float*)d_in[7];
    float* x = (float*)d_out;

    char* ws = (char*)d_ws;
    _Float16* qph  = (_Float16*)(ws);
    _Float16* qth  = (_Float16*)(ws + 4194304);
    float*  qd2    = (float*)(ws + 8388608);
    float*  cdot   = (float*)(ws + 8421376);
    float*  rowmax = (float*)(ws + 8683520);
    float*  Mb     = (float*)(ws + 8945664);
    float*  Zb     = (float*)(ws + 8945728);
    float*  q2c    = (float*)(ws + 8945792);

    k_prep_q<<<NB * QL / 4, 256, 0, stream>>>(q, w_q, b_q, w_cq, b_cq, qph, qd2);
    k_cdot<<<NB * CL / 4, 256, 0, stream>>>(c, w_c, b_c, cdot);
    k_tq<<<dim3(HD / 64, QL / 64, NB), 256, 0, stream>>>(q, qth);
    k_fused<<<dim3(CL / 64, NB), 512, 0, stream>>>(c, qph, qd2, qth, rowmax, x);
    k_batch_mz<<<NB, 256, 0, stream>>>(rowmax, cdot, Mb, Zb, q2c);
    k_q2c<<<NB * 64, 256, 0, stream>>>(c, rowmax, cdot, Mb, Zb, q2c);
    k_x03<<<NB * CL / 4, 256, 0, stream>>>(c, q2c, x);
}

// Round 4
// 450.882 us; speedup vs baseline: 1.0870x; 1.0475x over previous
//
#include <hip/hip_runtime.h>
#include <hip/hip_fp16.h>

// Problem constants (B, CLEN, QLEN, H)
constexpr int NB = 16;
constexpr int CL = 4096;
constexpr int QL = 512;
constexpr int HD = 256;

typedef _Float16 f16x8 __attribute__((ext_vector_type(8)));
typedef _Float16 f16x4 __attribute__((ext_vector_type(4)));
typedef float    f32x4 __attribute__((ext_vector_type(4)));

// ---------------------------------------------------------------------------
// Workspace layout (bytes):
//   qph    : q*w_cq fp16 [b][j][d]   @ 0          (4,194,304)
//   qth    : q fp16 [b][d][j]        @ 4,194,304  (4,194,304)
//   qd2    : q.w_q+b_q+b_cq fp32     @ 8,388,608  (32,768)
//   cdot   : c.w_c+b_c fp32          @ 8,421,376  (262,144)
//   rowmax : fp32 NB*CL              @ 8,683,520  (262,144)
//   Mb     : fp32 NB                 @ 8,945,664
//   Zb     : fp32 NB                 @ 8,945,728
//   q2c    : fp32 NB*HD              @ 8,945,792  (16,384)
// ---------------------------------------------------------------------------

// One wave per q-row: qph = fp16(q*w_cq) ; qd2 = q.w_q + b_q + b_cq
__global__ void k_prep_q(const float* __restrict__ q, const float* __restrict__ w_q,
                         const float* __restrict__ b_q, const float* __restrict__ w_cq,
                         const float* __restrict__ b_cq,
                         _Float16* __restrict__ qph, float* __restrict__ qd2) {
    int row  = blockIdx.x * 4 + (threadIdx.x >> 6);   // b*QL + j
    int lane = threadIdx.x & 63;
    float4 qv  = ((const float4*)(q + (size_t)row * HD))[lane];
    float4 wq  = ((const float4*)w_q)[lane];
    float4 wcq = ((const float4*)w_cq)[lane];
    f16x4 hv = {(_Float16)(qv.x * wcq.x), (_Float16)(qv.y * wcq.y),
                (_Float16)(qv.z * wcq.z), (_Float16)(qv.w * wcq.w)};
    *(f16x4*)(qph + (size_t)row * HD + lane * 4) = hv;
    float s = qv.x * wq.x + qv.y * wq.y + qv.z * wq.z + qv.w * wq.w;
    #pragma unroll
    for (int off = 32; off; off >>= 1) s += __shfl_down(s, off, 64);
    if (lane == 0) qd2[row] = s + b_q[0] + b_cq[0];
}

// One wave per c-row: cdot = c.w_c + b_c
__global__ void k_cdot(const float* __restrict__ c, const float* __restrict__ w_c,
                       const float* __restrict__ b_c, float* __restrict__ cdot) {
    int row  = blockIdx.x * 4 + (threadIdx.x >> 6);   // b*CL + i
    int lane = threadIdx.x & 63;
    float4 cv = ((const float4*)(c + (size_t)row * HD))[lane];
    float4 wv = ((const float4*)w_c)[lane];
    float s = cv.x * wv.x + cv.y * wv.y + cv.z * wv.z + cv.w * wv.w;
    #pragma unroll
    for (int off = 32; off; off >>= 1) s += __shfl_down(s, off, 64);
    if (lane == 0) cdot[row] = s + b_c[0];
}

// LDS transpose: qth[b][d][j] = fp16(q[b][j][d]); 64x64 tiles
__global__ void k_tq(const float* __restrict__ q, _Float16* __restrict__ qth) {
    __shared__ float tile[64][65];
    int b  = blockIdx.z;
    int d0 = blockIdx.x * 64;
    int j0 = blockIdx.y * 64;
    int t  = threadIdx.x;
    int rr = t >> 4, cseg = t & 15;
    #pragma unroll
    for (int p = 0; p < 4; ++p) {
        int r = rr + p * 16;   // j-row within tile
        float4 v = *(const float4*)(q + ((size_t)b * QL + j0 + r) * HD + d0 + cseg * 4);
        tile[r][cseg * 4 + 0] = v.x; tile[r][cseg * 4 + 1] = v.y;
        tile[r][cseg * 4 + 2] = v.z; tile[r][cseg * 4 + 3] = v.w;
    }
    __syncthreads();
    #pragma unroll
    for (int p = 0; p < 4; ++p) {
        int dr = rr + p * 16;  // d-row within tile
        f16x4 hv = {(_Float16)tile[cseg * 4 + 0][dr], (_Float16)tile[cseg * 4 + 1][dr],
                    (_Float16)tile[cseg * 4 + 2][dr], (_Float16)tile[cseg * 4 + 3][dr]};
        *(f16x4*)(qth + ((size_t)b * HD + d0 + dr) * QL + j0 + cseg * 4) = hv;
    }
}

// ---------------------------------------------------------------------------
// Fused kernel: per 128 c-rows of one batch, 8 waves (512 thr) as 2(wi)x4(wj):
//   GEMM1 (swapped): S^T = qph @ c^T. Wave (wi,wj): j in wj*128..+128,
//     i in wi*64..+64. qph staged cooperatively in K-chunks of 32 into
//     padded LDS [512][40] (80B rows, 16B-aligned, bank-spread).
//   softmax over j=512: lane-local + quad shfl + cross-wave (4 wj) LDS reduce.
//   P -> fp16 regs (32 VGPR); then two j-half passes: write PL [128][256]
//     (XOR-swizzled 64KB) -> GEMM2 partial c2q += P_half @ qth_half.
//   Epilogue: x[1]=c2q, x[2]=c*c2q. (x[0],x[3] in k_x03.)
// LDS 64KB static, time-shared: qphL [512][40] f16 (40,960) | redM/redZ
//   (2x2048 @0/@2048) | PL [128 rows x 512B] swizzled byte^=(i&7)<<4.
// ---------------------------------------------------------------------------
__launch_bounds__(512, 2)
__global__ void k_fused(const float* __restrict__ c, const _Float16* __restrict__ qph,
                        const float* __restrict__ qd2, const _Float16* __restrict__ qth,
                        float* __restrict__ rowmax, float* __restrict__ x) {
    __shared__ __align__(64) char smem[65536];
    _Float16 (*qphL)[40] = (_Float16 (*)[40])smem;

    const int b  = blockIdx.y;
    const int i0 = blockIdx.x * 128;
    const int t  = threadIdx.x;
    const int wave = t >> 6;
    const int wi = wave >> 2;          // 0..1 : i-block of 64
    const int wj = wave & 3;           // 0..3 : j-block of 128 (G1) / d-block of 64 (G2)
    const int ln   = t & 15;
    const int quad = (t >> 4) & 3;

    // ---------------- GEMM1: acc[mt][nt] = S^T fragment (j=row, i=col) --------
    f32x4 acc[8][4];
    #pragma unroll
    for (int mt = 0; mt < 8; ++mt)
        #pragma unroll
        for (int nt = 0; nt < 4; ++nt) acc[mt][nt] = (f32x4){0.f, 0.f, 0.f, 0.f};

    for (int ch = 0; ch < 8; ++ch) {               // K chunks of 32 over HD=256
        __syncthreads();
        #pragma unroll
        for (int p = 0; p < 4; ++p) {              // stage qph[b][*][ch*32..+32]
            int seg = t + p * 512;                 // 2048 segs = 512 rows x 4
            int row = seg >> 2, s = seg & 3;
            f16x8 hv = *(const f16x8*)(qph + ((size_t)b * QL + row) * HD + ch * 32 + s * 8);
            *(f16x8*)&qphL[row][s * 8] = hv;
        }
        __syncthreads();
        f16x8 bf[4];                               // B = c rows (fp32->fp16, L1-hot)
        #pragma unroll
        for (int nt = 0; nt < 4; ++nt) {
            const float* srcc = c + ((size_t)b * CL + i0 + wi * 64 + nt * 16 + ln) * HD
                              + ch * 32 + quad * 8;
            float4 v0 = *(const float4*)srcc;
            float4 v1 = *(const float4*)(srcc + 4);
            bf[nt] = (f16x8){(_Float16)v0.x, (_Float16)v0.y, (_Float16)v0.z, (_Float16)v0.w,
                             (_Float16)v1.x, (_Float16)v1.y, (_Float16)v1.z, (_Float16)v1.w};
        }
        #pragma unroll
        for (int mt = 0; mt < 8; ++mt) {           // A = qph rows (j) from LDS
            f16x8 af = *(const f16x8*)&qphL[wj * 128 + mt * 16 + ln][quad * 8];
            #pragma unroll
            for (int nt = 0; nt < 4; ++nt)
                acc[mt][nt] = __builtin_amdgcn_mfma_f32_16x16x32_f16(af, bf[nt], acc[mt][nt], 0, 0, 0);
        }
    }
    __syncthreads();                               // qphL dead; overlay reduce arrays
    // lane holds: j = wj*128 + mt*16 + quad*4 + r ; i = wi*64 + nt*16 + ln

    float* redM = (float*)smem;                    // [4][128]
    float* redZ = (float*)(smem + 2048);           // [4][128]
    const int il = wi * 64 + (t & 15);             // i-local base (with nt*16 added)

    // ---------------- softmax over j (512) ------------------------------------
    float m[4];
    #pragma unroll
    for (int nt = 0; nt < 4; ++nt) m[nt] = -1e30f;
    #pragma unroll
    for (int mt = 0; mt < 8; ++mt) {
        float4 qv = *(const float4*)(qd2 + b * QL + wj * 128 + mt * 16 + quad * 4);
        #pragma unroll
        for (int nt = 0; nt < 4; ++nt) {
            acc[mt][nt][0] += qv.x; acc[mt][nt][1] += qv.y;
            acc[mt][nt][2] += qv.z; acc[mt][nt][3] += qv.w;
            m[nt] = fmaxf(m[nt], fmaxf(fmaxf(acc[mt][nt][0], acc[mt][nt][1]),
                                       fmaxf(acc[mt][nt][2], acc[mt][nt][3])));
        }
    }
    #pragma unroll
    for (int nt = 0; nt < 4; ++nt) {               // reduce over quads
        m[nt] = fmaxf(m[nt], __shfl_xor(m[nt], 16, 64));
        m[nt] = fmaxf(m[nt], __shfl_xor(m[nt], 32, 64));
    }
    if (quad == 0) {
        #pragma unroll
        for (int nt = 0; nt < 4; ++nt) redM[wj * 128 + il + nt * 16] = m[nt];
    }
    __syncthreads();
    #pragma unroll
    for (int nt = 0; nt < 4; ++nt) {
        float mm = redM[il + nt * 16];
        #pragma unroll
        for (int w = 1; w < 4; ++w) mm = fmaxf(mm, redM[w * 128 + il + nt * 16]);
        m[nt] = mm;
    }
    if (wj == 0 && quad == 0) {
        #pragma unroll
        for (int nt = 0; nt < 4; ++nt)
            rowmax[(size_t)b * CL + i0 + il + nt * 16] = m[nt];
    }
    float z[4] = {0.f, 0.f, 0.f, 0.f};
    #pragma unroll
    for (int mt = 0; mt < 8; ++mt)
        #pragma unroll
        for (int nt = 0; nt < 4; ++nt) {
            #pragma unroll
            for (int r = 0; r < 4; ++r) {
                float e = __expf(acc[mt][nt][r] - m[nt]);
                acc[mt][nt][r] = e;
                z[nt] += e;
            }
        }
    #pragma unroll
    for (int nt = 0; nt < 4; ++nt) {
        z[nt] += __shfl_xor(z[nt], 16, 64);
        z[nt] += __shfl_xor(z[nt], 32, 64);
    }
    if (quad == 0) {
        #pragma unroll
        for (int nt = 0; nt < 4; ++nt) redZ[wj * 128 + il + nt * 16] = z[nt];
    }
    __syncthreads();
    f16x4 ph[8][4];                                // P in fp16 regs (32 VGPR)
    {
        float inv[4];
        #pragma unroll
        for (int nt = 0; nt < 4; ++nt) {
            float zz = redZ[il + nt * 16];
            #pragma unroll
            for (int w = 1; w < 4; ++w) zz += redZ[w * 128 + il + nt * 16];
            inv[nt] = 1.0f / zz;
        }
        #pragma unroll
        for (int mt = 0; mt < 8; ++mt)
            #pragma unroll
            for (int nt = 0; nt < 4; ++nt)
                ph[mt][nt] = (f16x4){(_Float16)(acc[mt][nt][0] * inv[nt]),
                                     (_Float16)(acc[mt][nt][1] * inv[nt]),
                                     (_Float16)(acc[mt][nt][2] * inv[nt]),
                                     (_Float16)(acc[mt][nt][3] * inv[nt])};
    }

    // ---------------- GEMM2 in two j-half passes -------------------------------
    f32x4 acc2[4][4];
    #pragma unroll
    for (int it = 0; it < 4; ++it)
        #pragma unroll
        for (int dt = 0; dt < 4; ++dt) acc2[it][dt] = (f32x4){0.f, 0.f, 0.f, 0.f};

    const _Float16* qthb = qth + (size_t)b * HD * QL;
    #pragma unroll
    for (int p = 0; p < 2; ++p) {
        __syncthreads();                           // prev readers done (redZ / PL)
        if ((wj >> 1) == p) {                      // 4 waves write this j-half
            #pragma unroll
            for (int mt = 0; mt < 8; ++mt) {
                int jl = (wj & 1) * 128 + mt * 16 + quad * 4;   // j-local in half
                #pragma unroll
                for (int nt = 0; nt < 4; ++nt) {
                    int i = il + nt * 16;
                    int byte = (i << 9) + (jl << 1);
                    byte ^= (i & 7) << 4;
                    *(f16x4*)(smem + byte) = ph[mt][nt];
                }
            }
        }
        __syncthreads();
        #pragma unroll 2
        for (int kc = 0; kc < 8; ++kc) {           // K chunks of 32 over half (256)
            f16x8 af[4], bf[4];
            #pragma unroll
            for (int it = 0; it < 4; ++it) {       // A = P rows (i), LDS swizzled
                int i = wi * 64 + it * 16 + ln;
                int byte = (i << 9) + kc * 64 + quad * 16;
                byte ^= (i & 7) << 4;
                af[it] = *(const f16x8*)(smem + byte);
            }
            #pragma unroll
            for (int dt = 0; dt < 4; ++dt)         // B = qth rows (d), global (L2-hot)
                bf[dt] = *(const f16x8*)(qthb + (size_t)(wj * 64 + dt * 16 + ln) * QL
                                         + p * 256 + kc * 32 + quad * 8);
            #pragma unroll
            for (int it = 0; it < 4; ++it)
                #pragma unroll
                for (int dt = 0; dt < 4; ++dt)
                    acc2[it][dt] = __builtin_amdgcn_mfma_f32_16x16x32_f16(af[it], bf[dt], acc2[it][dt], 0, 0, 0);
        }
    }

    // ---------------- epilogue: x[1]=c2q, x[2]=c*c2q ---------------------------
    #pragma unroll
    for (int it = 0; it < 4; ++it) {
        #pragma unroll
        for (int r = 0; r < 4; ++r) {
            int i = i0 + wi * 64 + it * 16 + quad * 4 + r;
            const float* crow = c + ((size_t)b * CL + i) * HD;
            float* xrow = x + ((size_t)b * CL + i) * (4 * HD);
            #pragma unroll
            for (int dt = 0; dt < 4; ++dt) {
                int d = wj * 64 + dt * 16 + ln;
                float cv = crow[d];
                float a  = acc2[it][dt][r];
                xrow[HD + d]     = a;
                xrow[2 * HD + d] = cv * a;
            }
        }
    }
}

// Per-batch M,Z over i of (rowmax + cdot); also zero-init q2c accumulators
__global__ void k_batch_mz(const float* __restrict__ rowmax, const float* __restrict__ cdot,
                           float* __restrict__ Mb, float* __restrict__ Zb,
                           float* __restrict__ q2c) {
    int b = blockIdx.x, t = threadIdx.x;
    q2c[b * HD + t] = 0.f;
    float vals[16];
    float m = -1e30f;
    #pragma unroll
    for (int k = 0; k < 16; ++k) {
        int i = t + k * 256;
        vals[k] = rowmax[b * CL + i] + cdot[b * CL + i];
        m = fmaxf(m, vals[k]);
    }
    __shared__ float redm[4], redz[4];
    #pragma unroll
    for (int off = 32; off; off >>= 1) m = fmaxf(m, __shfl_xor(m, off, 64));
    if ((t & 63) == 0) redm[t >> 6] = m;
    __syncthreads();
    m = fmaxf(fmaxf(redm[0], redm[1]), fmaxf(redm[2], redm[3]));
    float z = 0.f;
    #pragma unroll
    for (int k = 0; k < 16; ++k) z += __expf(vals[k] - m);
    #pragma unroll
    for (int off = 32; off; off >>= 1) z += __shfl_xor(z, off, 64);
    if ((t & 63) == 0) redz[t >> 6] = z;
    __syncthreads();
    if (t == 0) { Mb[b] = m; Zb[b] = redz[0] + redz[1] + redz[2] + redz[3]; }
}

// q2c[b][d] = sum_i softmax_i(rowmax+cdot) * c[b][i][d]
__global__ void k_q2c(const float* __restrict__ c, const float* __restrict__ rowmax,
                      const float* __restrict__ cdot, const float* __restrict__ Mb,
                      const float* __restrict__ Zb, float* __restrict__ q2c) {
    int b = blockIdx.x >> 6, slab = blockIdx.x & 63;
    int dd = threadIdx.x;
    float M = Mb[b], invZ = 1.0f / Zb[b];
    float acc = 0.f;
    for (int r = 0; r < 64; ++r) {
        int i = slab * 64 + r;
        float w = __expf(rowmax[b * CL + i] + cdot[b * CL + i] - M);
        acc += w * c[((size_t)b * CL + i) * HD + dd];
    }
    atomicAdd(&q2c[b * HD + dd], acc * invZ);
}

// x[0] and x[3] quarters: x[...][d] = c ; x[...][3H+d] = c * q2c
__global__ void k_x03(const float* __restrict__ c, const float* __restrict__ q2c,
                      float* __restrict__ x) {
    int row  = blockIdx.x * 4 + (threadIdx.x >> 6);   // b*CL + i
    int lane = threadIdx.x & 63;
    int b = row >> 12;                                 // CL = 4096
    float4 cv = ((const float4*)(c + (size_t)row * HD))[lane];
    float4 qv = ((const float4*)(q2c + b * HD))[lane];
    float4 o  = {cv.x * qv.x, cv.y * qv.y, cv.z * qv.z, cv.w * qv.w};
    float* xrow = x + (size_t)row * (4 * HD);
    ((float4*)xrow)[lane]            = cv;
    ((float4*)(xrow + 3 * HD))[lane] = o;
}

extern "C" void kernel_launch(void* const* d_in, const int* in_sizes, int n_in,
                              void* d_out, int out_size, void* d_ws, size_t ws_size,
                              hipStream_t stream) {
    const float* c    = (const float*)d_in[0];
    const float* q    = (const float*)d_in[1];
    const float* w_c  = (const float*)d_in[2];
    const float* b_c  = (const float*)d_in[3];
    const float* w_q  = (const float*)d_in[4];
    const float* b_q  = (const float*)d_in[5];
    const float* w_cq = (const float*)d_in[6];
    const float* b_cq = (const float*)d_in[7];
    float* x = (float*)d_out;

    char* ws = (char*)d_ws;
    _Float16* qph  = (_Float16*)(ws);
    _Float16* qth  = (_Float16*)(ws + 4194304);
    float*  qd2    = (float*)(ws + 8388608);
    float*  cdot   = (float*)(ws + 8421376);
    float*  rowmax = (float*)(ws + 8683520);
    float*  Mb     = (float*)(ws + 8945664);
    float*  Zb     = (float*)(ws + 8945728);
    float*  q2c    = (float*)(ws + 8945792);

    k_prep_q<<<NB * QL / 4, 256, 0, stream>>>(q, w_q, b_q, w_cq, b_cq, qph, qd2);
    k_cdot<<<NB * CL / 4, 256, 0, stream>>>(c, w_c, b_c, cdot);
    k_tq<<<dim3(HD / 64, QL / 64, NB), 256, 0, stream>>>(q, qth);
    k_fused<<<dim3(CL / 128, NB), 512, 0, stream>>>(c, qph, qd2, qth, rowmax, x);
    k_batch_mz<<<NB, 256, 0, stream>>>(rowmax, cdot, Mb, Zb, q2c);
    k_q2c<<<NB * 64, 256, 0, stream>>>(c, rowmax, cdot, Mb, Zb, q2c);
    k_x03<<<NB * CL / 4, 256, 0, stream>>>(c, q2c, x);
}